// Round 2
// 506.568 us; speedup vs baseline: 1.2141x; 1.2141x over previous
//
#include <hip/hip_runtime.h>

// ---- shapes (hard-coded to this problem) ----
#define TT 64
#define SLOT 320          // OUT + ACT
#define CONCAT 1536       // IN + 4*SLOT
#define ROWPAD 1544       // CONCAT + 8 bf16 pad
#define XSHORTS (16 * ROWPAD)        // 24704 shorts = 49408 B

typedef __attribute__((ext_vector_type(8))) short bf16x8;
typedef __attribute__((ext_vector_type(4))) short short4v;
typedef __attribute__((ext_vector_type(4))) float float4v;

__device__ __forceinline__ short f2bf(float f) {
    union { float f; unsigned u; } v;
    v.f = f;
    unsigned r = v.u + 0x7fffu + ((v.u >> 16) & 1u);  // RNE
    return (short)(r >> 16);
}

// Repack W (256 x 1536 fp32) -> bf16 MFMA-B-fragment order:
// frag (tl 0..15, kb 0..47): lane L holds W[tl*16 + (L&15)][kb*32 + (L>>4)*8 + j], j=0..7.
// Wave tl's 48 frags are one contiguous 48KB stream.
__global__ void wprep_kernel(const float* __restrict__ W, short* __restrict__ Wb) {
    int idx = blockIdx.x * 256 + threadIdx.x;       // 0 .. 49151 (16*48*64)
    if (idx >= 16 * 48 * 64) return;
    int lane = idx & 63;
    int kb   = (idx >> 6) % 48;
    int tl   = idx / (48 * 64);
    int n = tl * 16 + (lane & 15);
    int k = kb * 32 + (lane >> 4) * 8;
    const float* src = W + (size_t)n * CONCAT + k;
    short4v s0, s1;
    s0.x = f2bf(src[0]); s0.y = f2bf(src[1]); s0.z = f2bf(src[2]); s0.w = f2bf(src[3]);
    s1.x = f2bf(src[4]); s1.y = f2bf(src[5]); s1.z = f2bf(src[6]); s1.w = f2bf(src[7]);
    short* dst = Wb + (size_t)idx * 8;
    *(short4v*)dst = s0;
    *(short4v*)(dst + 4) = s1;
}

// 64 WGs x 1024 threads (16 waves), 16 seqs/WG. Wave w owns out-tile w (16 outs),
// full K=1536 -> no cross-wave reduction.
// W path this version: NO LDS ring. kb 0..7 live in VGPRs for the whole kernel
// (loaded once); kb 8..47 streamed global->VGPR each step through an 8-deep
// register ring (buffer loads to regs; compiler-tracked vmcnt). This removes
// the 1.5 MB/step LDS round-trip (DMA-write + ring-read) that bound the
// previous version; LDS now carries only the A-fragments (~790 KB/step).
__global__ __launch_bounds__(1024) void hist_kernel(
    const float* __restrict__ o,    // (B,T,P,256)
    const float* __restrict__ act,  // (B,T,P,64)
    const float* __restrict__ bias, // (256)
    const short* __restrict__ Wb,   // packed bf16 B-frags, [tl][kb][lane][8]
    float* __restrict__ out)        // (B,T,P,256)
{
    __shared__ short lds[XSHORTS];   // 49408 B (ring removed)

    const int tid  = threadIdx.x;
    const int wave = tid >> 6;
    const int lane = tid & 63;
    const int q    = lane >> 4;
    const int ln   = lane & 15;
    const int bb   = blockIdx.x >> 2;
    const int p0   = (blockIdx.x & 3) << 4;

    const short* wsrc = Wb + (size_t)wave * 48 * 512;    // contiguous 48KB W slice

    // zero z/a history (cols 0..1279 of each seq row)
    for (int i = tid; i < 16 * 640; i += 1024) {
        int row = i / 640, c = i % 640;
        *(float*)&lds[row * ROWPAD + c * 2] = 0.f;
    }

    const float bv = bias[wave * 16 + ln];
    const int arow = ln * ROWPAD + (q << 3);

    // resident W frags: kb 0..7, held in 32 VGPRs for the whole kernel
    bf16x8 wres[8];
#pragma unroll
    for (int kb = 0; kb < 8; ++kb)
        wres[kb] = *(const bf16x8*)(wsrc + kb * 512 + lane * 8);

    // streamed-W register ring (kb 8..47 -> stream index s = kb-8, slot s&7)
    bf16x8 wr[8];

// logical W column kb -> physical LDS column (history slots rotate with t)
#define CLCOL(kb) ((kb) < 40 \
        ? pbase[(kb) / 10] + (((kb) % 10) < 8 ? (((kb) % 10) << 5) : (256 + ((((kb) % 10) - 8) << 5))) \
        : 1280 + (((kb) - 40) << 5))

// issue stream load s (kb = 8+s) into ring slot s&7 (global -> VGPR)
#define ISSUE(s) wr[(s) & 7] = *(const bf16x8*)(wst + (s) * 512 + lane * 8);

// resident pair: kbs 2J, 2J+1 from wres
#define RPAIR(J) { \
        bf16x8 af0 = *(const bf16x8*)&lds[arow + CLCOL(2*(J))]; \
        bf16x8 af1 = *(const bf16x8*)&lds[arow + CLCOL(2*(J)+1)]; \
        acc_e = __builtin_amdgcn_mfma_f32_16x16x32_bf16(af0, wres[2*(J)],   acc_e, 0, 0, 0); \
        acc_o = __builtin_amdgcn_mfma_f32_16x16x32_bf16(af1, wres[2*(J)+1], acc_o, 0, 0, 0); \
    }

// streamed pair: consume ring slots, then refill them (WAR on the same regs
// keeps ordering; refill is consumed 4 pairs (~600-800 cyc) later)
#define SPAIR(J) { \
        constexpr int s0 = 2*((J) - 4); \
        bf16x8 af0 = *(const bf16x8*)&lds[arow + CLCOL(2*(J))]; \
        bf16x8 af1 = *(const bf16x8*)&lds[arow + CLCOL(2*(J)+1)]; \
        acc_e = __builtin_amdgcn_mfma_f32_16x16x32_bf16(af0, wr[s0 & 7],       acc_e, 0, 0, 0); \
        acc_o = __builtin_amdgcn_mfma_f32_16x16x32_bf16(af1, wr[(s0 + 1) & 7], acc_o, 0, 0, 0); \
        if constexpr (s0 + 8 <= 39) { ISSUE(s0 + 8) } \
        if constexpr (s0 + 9 <= 39) { ISSUE(s0 + 9) } \
    }

    for (int t = 0; t < TT; ++t) {
        const size_t tok = ((size_t)bb * TT + t) * 64 + p0;

        // stage o_t -> x o-region (bf16); a_t -> register
        {
            float4v ov = ((const float4v*)(o + tok * 256))[tid];
            int row = tid >> 6, col = (tid & 63) << 2;
            short4v s;
            s.x = f2bf(ov.x); s.y = f2bf(ov.y); s.z = f2bf(ov.z); s.w = f2bf(ov.w);
            *(short4v*)&lds[row * ROWPAD + 1280 + col] = s;
        }
        float aval = (act + tok * 64)[tid];

        __syncthreads();   // barrier alpha: o-region + prev-step z/a slot visible

        int pbase[4];
#pragma unroll
        for (int h = 0; h < 4; ++h) pbase[h] = ((h + t) & 3) * SLOT;

        float4v acc_e = {0.f, 0.f, 0.f, 0.f};
        float4v acc_o = acc_e;

        // opaque copy of the stream base (VGPR pair -- wsrc is per-wave, i.e.
        // VGPR-resident; "+s" here was an illegal VGPR->SGPR copy): defeats
        // LICM so the 40 t-invariant stream loads stay inside the t-loop.
        unsigned long long wp_ = (unsigned long long)(wsrc + 8 * 512);
        asm volatile("" : "+v"(wp_));
        const short* wst = (const short*)wp_;

        // prime the register ring (8 loads in flight), covered by 4 resident pairs
        ISSUE(0) ISSUE(1) ISSUE(2) ISSUE(3) ISSUE(4) ISSUE(5) ISSUE(6) ISSUE(7)

        RPAIR(0)  RPAIR(1)  RPAIR(2)  RPAIR(3)
        SPAIR(4)  SPAIR(5)  SPAIR(6)  SPAIR(7)  SPAIR(8)  SPAIR(9)
        SPAIR(10) SPAIR(11) SPAIR(12) SPAIR(13) SPAIR(14) SPAIR(15)
        SPAIR(16) SPAIR(17) SPAIR(18) SPAIR(19) SPAIR(20) SPAIR(21)
        SPAIR(22) SPAIR(23)

        __syncthreads();   // barrier beta: all A-reads done -> safe to overwrite slot t&3

        // epilogue: z -> global fp32; z,a -> LDS slot (t&3) as bf16
        const int pz = (t & 3) * SLOT;
        float* outp = out + tok * 256;
        float4v ze = acc_e, zo = acc_o;
#pragma unroll
        for (int r = 0; r < 4; ++r) {
            const int m = (q << 2) + r;               // C/D: row m = quad*4+reg (seq)
            const int n = (wave << 4) + ln;           // out index
            float z = ze[r] + zo[r] + bv;
            outp[(size_t)m * 256 + n] = z;
            lds[m * ROWPAD + pz + n] = f2bf(z);
        }
        lds[(tid >> 6) * ROWPAD + pz + 256 + (tid & 63)] = f2bf(aval);
        // next iteration's barrier alpha orders these writes before the next MFMA phase
    }
#undef SPAIR
#undef RPAIR
#undef ISSUE
#undef CLCOL
}

extern "C" void kernel_launch(void* const* d_in, const int* in_sizes, int n_in,
                              void* d_out, int out_size, void* d_ws, size_t ws_size,
                              hipStream_t stream) {
    const float* o  = (const float*)d_in[0];
    const float* a  = (const float*)d_in[1];
    const float* W  = (const float*)d_in[2];
    const float* b  = (const float*)d_in[3];
    short* Wb = (short*)d_ws;   // 786432 B used

    hipLaunchKernelGGL(wprep_kernel, dim3(192), dim3(256), 0, stream, W, Wb);
    hipLaunchKernelGGL(hist_kernel, dim3(64), dim3(1024), 0, stream,
                       o, a, b, Wb, (float*)d_out);
}

// Round 3
// 482.132 us; speedup vs baseline: 1.2757x; 1.0507x over previous
//
#include <hip/hip_runtime.h>

// ---- shapes (hard-coded to this problem) ----
#define TT 64
#define SLOT 320          // OUT + ACT
#define CONCAT 1536       // IN + 4*SLOT
#define ROWPAD 1544       // CONCAT + 8 bf16 pad
#define XSHORTS (16 * ROWPAD)        // 24704 shorts = 49408 B
#define SCRSHORTS 32768              // 64 KB f32 reduce scratch

typedef __attribute__((ext_vector_type(8))) short bf16x8;
typedef __attribute__((ext_vector_type(4))) short short4v;
typedef __attribute__((ext_vector_type(4))) float float4v;

__device__ __forceinline__ short f2bf(float f) {
    union { float f; unsigned u; } v;
    v.f = f;
    unsigned r = v.u + 0x7fffu + ((v.u >> 16) & 1u);  // RNE
    return (short)(r >> 16);
}

// Repack W (256 x 1536 fp32) -> bf16 MFMA-B-fragment order:
// frag (tl 0..15, kb 0..47): lane L holds W[tl*16 + (L&15)][kb*32 + (L>>4)*8 + j], j=0..7.
__global__ void wprep_kernel(const float* __restrict__ W, short* __restrict__ Wb) {
    int idx = blockIdx.x * 256 + threadIdx.x;       // 0 .. 49151 (16*48*64)
    if (idx >= 16 * 48 * 64) return;
    int lane = idx & 63;
    int kb   = (idx >> 6) % 48;
    int tl   = idx / (48 * 64);
    int n = tl * 16 + (lane & 15);
    int k = kb * 32 + (lane >> 4) * 8;
    const float* src = W + (size_t)n * CONCAT + k;
    short4v s0, s1;
    s0.x = f2bf(src[0]); s0.y = f2bf(src[1]); s0.z = f2bf(src[2]); s0.w = f2bf(src[3]);
    s1.x = f2bf(src[4]); s1.y = f2bf(src[5]); s1.z = f2bf(src[6]); s1.w = f2bf(src[7]);
    short* dst = Wb + (size_t)idx * 8;
    *(short4v*)dst = s0;
    *(short4v*)(dst + 4) = s1;
}

// 64 WGs x 1024 threads (16 waves), 16 seqs/WG.
// NEW decomposition (A-reuse): wave (c = w&3, g = w>>2) owns out-tiles 4c..4c+3
// and K-block kb in [12g, 12g+12). Each A-frag (x) LDS read feeds 4 MFMAs
// (was 1) -> A-LDS traffic 768 -> 192 reads/CU/step. K now split 4-ways ->
// f32 partial accs reduced through a 64KB LDS scratch (+1 barrier).
// W: 8 frags resident in VGPRs, 40/wave streamed global->VGPR ring per step.
__global__ __launch_bounds__(1024) void hist_kernel(
    const float* __restrict__ o,    // (B,T,P,256)
    const float* __restrict__ act,  // (B,T,P,64)
    const float* __restrict__ bias, // (256)
    const short* __restrict__ Wb,   // packed bf16 B-frags, [tl][kb][lane][8]
    float* __restrict__ out)        // (B,T,P,256)
{
    __shared__ short lds[XSHORTS + SCRSHORTS];   // 49408 + 65536 = 114944 B

    const int tid  = threadIdx.x;
    const int wave = tid >> 6;
    const int lane = tid & 63;
    const int q    = lane >> 4;
    const int ln   = lane & 15;
    const int bb   = blockIdx.x >> 2;
    const int p0   = (blockIdx.x & 3) << 4;

    const int c = wave & 3;      // out-column group -> tiles 4c..4c+3
    const int g = wave >> 2;     // K-group -> kb 12g..12g+11
    const int sg = __builtin_amdgcn_readfirstlane(g);   // SGPR copy for SALU col math

    float* scr = (float*)&lds[XSHORTS];   // [tile 16][g 4][lane 64][4 f32]

    // zero z/a history (cols 0..1279 of each seq row)
    for (int i = tid; i < 16 * 640; i += 1024) {
        int row = i / 640, cc = i % 640;
        *(float*)&lds[row * ROWPAD + cc * 2] = 0.f;
    }

    const float bv = bias[wave * 16 + ln];         // final tile = wave
    const int arow = ln * ROWPAD + (q << 3);

    // W base for this wave: tile (4c+i) is i*24576 shorts away, kb j is j*512 away
    const short* wbase = Wb + ((size_t)(4 * c) * 48 + 12 * g) * 512 + lane * 8;

    // resident W frags: j = 0,1 (8 frags, 32 VGPR), loaded once
    bf16x8 wres[2][4];
#pragma unroll
    for (int i = 0; i < 4; ++i) {
        wres[0][i] = *(const bf16x8*)(wbase + i * 24576);
        wres[1][i] = *(const bf16x8*)(wbase + i * 24576 + 512);
    }

    // streamed-W register ring: frag (j,i) -> slot (4j+i)&7
    bf16x8 wr[8];

// logical W column kb = 12*sg + J -> physical LDS column (history rotates with t).
// All t-invariant parts (kb/10, kb%10, region select) are SALU + LICM-hoisted.
#define KB(J) (12 * sg + (J))
#define CL(J) (KB(J) < 40 \
        ? (((KB(J) / 10 + t) & 3) * SLOT + ((KB(J) % 10) < 8 ? ((KB(J) % 10) << 5) \
                                                             : (256 + (((KB(J) % 10) - 8) << 5)))) \
        : (1280 + ((KB(J) - 40) << 5)))

// issue the 4 B-frag loads for k-step JT (global -> VGPR ring)
#define ISSUE4(JT) { \
        wr[(4*(JT)+0)&7] = *(const bf16x8*)(sb + (JT)*512); \
        wr[(4*(JT)+1)&7] = *(const bf16x8*)(sb + 24576 + (JT)*512); \
        wr[(4*(JT)+2)&7] = *(const bf16x8*)(sb + 49152 + (JT)*512); \
        wr[(4*(JT)+3)&7] = *(const bf16x8*)(sb + 73728 + (JT)*512); }

// k-step from resident frags (J = 0,1): one A-read feeds 4 MFMAs
#define KSTEP_R(J) { \
        bf16x8 af = *(const bf16x8*)&lds[arow + CL(J)]; \
        acc0 = __builtin_amdgcn_mfma_f32_16x16x32_bf16(af, wres[J][0], acc0, 0, 0, 0); \
        acc1 = __builtin_amdgcn_mfma_f32_16x16x32_bf16(af, wres[J][1], acc1, 0, 0, 0); \
        acc2 = __builtin_amdgcn_mfma_f32_16x16x32_bf16(af, wres[J][2], acc2, 0, 0, 0); \
        acc3 = __builtin_amdgcn_mfma_f32_16x16x32_bf16(af, wres[J][3], acc3, 0, 0, 0); }

// k-step from ring (J = 2..11); consume slots then re-issue them for J+2
#define KSTEP_S(J) { \
        bf16x8 af = *(const bf16x8*)&lds[arow + CL(J)]; \
        acc0 = __builtin_amdgcn_mfma_f32_16x16x32_bf16(af, wr[(4*(J)+0)&7], acc0, 0, 0, 0); \
        acc1 = __builtin_amdgcn_mfma_f32_16x16x32_bf16(af, wr[(4*(J)+1)&7], acc1, 0, 0, 0); \
        acc2 = __builtin_amdgcn_mfma_f32_16x16x32_bf16(af, wr[(4*(J)+2)&7], acc2, 0, 0, 0); \
        acc3 = __builtin_amdgcn_mfma_f32_16x16x32_bf16(af, wr[(4*(J)+3)&7], acc3, 0, 0, 0); \
        if constexpr ((J) + 2 <= 11) { ISSUE4((J) + 2) } }

    for (int t = 0; t < TT; ++t) {
        const size_t tok = ((size_t)bb * TT + t) * 64 + p0;

        // opaque per-t stream base: the 40 W loads are t-invariant addresses;
        // without this LICM hoists them into 160 registers -> spill
        unsigned long long sb_ = (unsigned long long)wbase;
        asm volatile("" : "+v"(sb_));
        const short* sb = (const short*)sb_;

        // prime the ring for k-steps 2,3 (8 loads in flight before the barrier)
        ISSUE4(2) ISSUE4(3)

        // stage o_t -> x o-region (bf16); a_t -> register
        {
            float4v ov = ((const float4v*)(o + tok * 256))[tid];
            int row = tid >> 6, col = (tid & 63) << 2;
            short4v s;
            s.x = f2bf(ov.x); s.y = f2bf(ov.y); s.z = f2bf(ov.z); s.w = f2bf(ov.w);
            *(short4v*)&lds[row * ROWPAD + 1280 + col] = s;
        }
        float aval = (act + tok * 64)[tid];

        __syncthreads();   // barrier alpha: o-region + prev-step z/a slot visible

        float4v acc0 = {0.f, 0.f, 0.f, 0.f};
        float4v acc1 = acc0, acc2 = acc0, acc3 = acc0;

        KSTEP_R(0)  KSTEP_R(1)
        KSTEP_S(2)  KSTEP_S(3)  KSTEP_S(4)  KSTEP_S(5)  KSTEP_S(6)
        KSTEP_S(7)  KSTEP_S(8)  KSTEP_S(9)  KSTEP_S(10) KSTEP_S(11)

        // write K-partials: tile (4c+i), group g, 16B/lane
        *(float4v*)&scr[(((4 * c + 0) * 4 + g) * 64 + lane) * 4] = acc0;
        *(float4v*)&scr[(((4 * c + 1) * 4 + g) * 64 + lane) * 4] = acc1;
        *(float4v*)&scr[(((4 * c + 2) * 4 + g) * 64 + lane) * 4] = acc2;
        *(float4v*)&scr[(((4 * c + 3) * 4 + g) * 64 + lane) * 4] = acc3;

        __syncthreads();   // barrier gamma: partials visible; all A-reads done

        // wave w reduces tile w (4 K-partials) -> z
        float4v s0 = *(const float4v*)&scr[((wave * 4 + 0) * 64 + lane) * 4];
        float4v s1 = *(const float4v*)&scr[((wave * 4 + 1) * 64 + lane) * 4];
        float4v s2 = *(const float4v*)&scr[((wave * 4 + 2) * 64 + lane) * 4];
        float4v s3 = *(const float4v*)&scr[((wave * 4 + 3) * 64 + lane) * 4];
        float4v zz = (s0 + s1) + (s2 + s3);

        // epilogue: z -> global fp32; z,a -> LDS slot (t&3) as bf16
        const int pz = (t & 3) * SLOT;
        float* outp = out + tok * 256;
#pragma unroll
        for (int r = 0; r < 4; ++r) {
            const int m = (q << 2) + r;               // C/D: row m = quad*4+reg (seq)
            const int n = (wave << 4) + ln;           // out index (tile = wave)
            float z = zz[r] + bv;
            outp[(size_t)m * 256 + n] = z;
            lds[m * ROWPAD + pz + n] = f2bf(z);
        }
        lds[(tid >> 6) * ROWPAD + pz + 256 + (tid & 63)] = f2bf(aval);
        // next iteration's barrier alpha orders these writes before the next MFMA phase
    }
#undef KSTEP_S
#undef KSTEP_R
#undef ISSUE4
#undef CL
#undef KB
}

extern "C" void kernel_launch(void* const* d_in, const int* in_sizes, int n_in,
                              void* d_out, int out_size, void* d_ws, size_t ws_size,
                              hipStream_t stream) {
    const float* o  = (const float*)d_in[0];
    const float* a  = (const float*)d_in[1];
    const float* W  = (const float*)d_in[2];
    const float* b  = (const float*)d_in[3];
    short* Wb = (short*)d_ws;   // 786432 B used

    hipLaunchKernelGGL(wprep_kernel, dim3(192), dim3(256), 0, stream, W, Wb);
    hipLaunchKernelGGL(hist_kernel, dim3(64), dim3(1024), 0, stream,
                       o, a, b, Wb, (float*)d_out);
}